// Round 1
// baseline (302.924 us; speedup 1.0000x reference)
//
#include <hip/hip_runtime.h>

// Swin shifted-window MHSA, fully fused per-window kernel.
// 1 block = 1 window (S=64 tokens, C=128), 256 threads = 4 waves.
// bf16 MFMA (16x16x32) for all GEMMs; fp32 accumulate; fp32 output.

typedef __attribute__((ext_vector_type(8))) short bf16x8;   // 8 bf16 = 4 VGPR
typedef __attribute__((ext_vector_type(4))) float f32x4;    // MFMA C/D

#define MFMA16(a, b, c) __builtin_amdgcn_mfma_f32_16x16x32_bf16((a), (b), (c), 0, 0, 0)

__device__ __forceinline__ unsigned short f2bf(float f) {
  union { float f; unsigned int u; } v; v.f = f;
  unsigned int r = v.u + 0x7fffu + ((v.u >> 16) & 1u);   // RNE
  return (unsigned short)(r >> 16);
}

// LDS layout (bytes). Rows are XOR-swizzled: byte ^= ((row&7)<<4).
#define XP_OFF 0        // 32KB: Xw [64][128]bf16 (phase A/B), then P [4][64][64]bf16 (C/D)
#define Q_OFF  32768    // 16KB: Q [64][128]bf16
#define K_OFF  49152    // 16KB: K [64][128]bf16, then attn-out (phase E/F)
#define VT_OFF 65536    // 16KB: Vt [128][64]bf16 (V transposed)
#define LDS_BYTES 81920

// prep: transpose weights to bf16 Wt[n][k] (4 matrices) + expand rel-pos bias to [4][64][64] f32.
__global__ void prep_kernel(const float* __restrict__ wq, const float* __restrict__ wk,
                            const float* __restrict__ wv, const float* __restrict__ wo,
                            const float* __restrict__ bias_table,
                            unsigned short* __restrict__ wt, float* __restrict__ bias_full) {
  int tid = blockIdx.x * 256 + threadIdx.x;            // 65536 threads
  int m = tid >> 14, idx = tid & 16383;
  int n = idx >> 7, k = idx & 127;
  const float* w = (m == 0) ? wq : (m == 1) ? wk : (m == 2) ? wv : wo;
  wt[m * 16384 + n * 128 + k] = f2bf(w[k * 128 + n]);
  if (tid < 16384) {                                    // bias_full[h][s1][s2]
    int h = tid >> 12, r = tid & 4095;
    int s1 = r >> 6, s2 = r & 63;
    int rel = ((s1 >> 3) - (s2 >> 3) + 7) * 15 + ((s1 & 7) - (s2 & 7) + 7);
    bias_full[tid] = bias_table[rel * 4 + h];
  }
}

// [64x128] = Xw(LDS) @ Wt + bias, result bf16 into LDS. DEST: 0=Q, 1=K, 2=Vt(transposed)
template <int DEST>
__device__ __forceinline__ void proj_gemm(char* smem, const unsigned short* __restrict__ wmat,
                                          const float* __restrict__ bias, int wave, int lane) {
  const int g = lane >> 4, c16 = lane & 15;
  f32x4 z = {0.f, 0.f, 0.f, 0.f};
  f32x4 acc[8];
#pragma unroll
  for (int nt = 0; nt < 8; ++nt) acc[nt] = z;
  const int arow = wave * 16 + c16;
  const int asw = (arow & 7) << 4;
#pragma unroll
  for (int kk = 0; kk < 4; ++kk) {
    bf16x8 a = *(const bf16x8*)(smem + XP_OFF + arow * 256 + ((kk * 64 + g * 16) ^ asw));
#pragma unroll
    for (int nt = 0; nt < 8; ++nt) {
      bf16x8 b = *(const bf16x8*)(wmat + (nt * 16 + c16) * 128 + kk * 32 + g * 8);
      acc[nt] = MFMA16(a, b, acc[nt]);
    }
  }
#pragma unroll
  for (int nt = 0; nt < 8; ++nt) {
    const int n = nt * 16 + c16;
    const float bn = bias[n];
#pragma unroll
    for (int r = 0; r < 4; ++r) {
      const int row = wave * 16 + g * 4 + r;          // C/D: row=(l>>4)*4+reg (+ M-tile)
      unsigned short hv = f2bf(acc[nt][r] + bn);
      if (DEST == 2) {                                 // Vt[n][row]
        *(unsigned short*)(smem + VT_OFF + n * 128 + ((row * 2) ^ ((n & 7) << 4))) = hv;
      } else {
        *(unsigned short*)(smem + (DEST == 0 ? Q_OFF : K_OFF) + row * 256 +
                           ((n * 2) ^ ((row & 7) << 4))) = hv;
      }
    }
  }
}

__global__ __launch_bounds__(256) void winattn_kernel(
    const float* __restrict__ x,
    const float* __restrict__ bq, const float* __restrict__ bk,
    const float* __restrict__ bv, const float* __restrict__ bo,
    const unsigned short* __restrict__ wt,
    const float* __restrict__ bias_full,
    const int* __restrict__ shiftp,
    float* __restrict__ out) {
  __shared__ __align__(16) char smem[LDS_BYTES];
  const int tid = threadIdx.x;
  const int wave = tid >> 6, lane = tid & 63;
  const int g = lane >> 4, c16 = lane & 15;
  const int win = blockIdx.x;
  const int b = win >> 8, widx = win & 255;
  const int wh = widx >> 4, ww = widx & 15;
  const int shift = shiftp[0];
  const int ss = shift ? 4 : 0;

  // ---- Phase A: gather shifted window tokens -> Xw (bf16, swizzled) ----
#pragma unroll
  for (int it = 0; it < 4; ++it) {
    int cid = tid + it * 256;                 // 1024 chunks of 8 channels
    int s = cid >> 4, cc = (cid & 15) << 3;
    int r0 = (wh * 8 + (s >> 3) + ss) & 127;  // roll(-ss): src = pos + ss (mod 128)
    int c0 = (ww * 8 + (s & 7) + ss) & 127;
    const float* src = x + ((b * 16384 + r0 * 128 + c0) * 128 + cc);
    float4 lo = *(const float4*)src;
    float4 hi = *(const float4*)(src + 4);
    bf16x8 v;
    v[0] = (short)f2bf(lo.x); v[1] = (short)f2bf(lo.y);
    v[2] = (short)f2bf(lo.z); v[3] = (short)f2bf(lo.w);
    v[4] = (short)f2bf(hi.x); v[5] = (short)f2bf(hi.y);
    v[6] = (short)f2bf(hi.z); v[7] = (short)f2bf(hi.w);
    *(bf16x8*)(smem + XP_OFF + s * 256 + ((cc * 2) ^ ((s & 7) << 4))) = v;
  }
  __syncthreads();

  // ---- Phase B: Q,K,V projections ----
  proj_gemm<0>(smem, wt, bq, wave, lane);
  proj_gemm<1>(smem, wt + 16384, bk, wave, lane);
  proj_gemm<2>(smem, wt + 32768, bv, wave, lane);
  __syncthreads();

  // ---- Phase C: scores + softmax (wave h = head h) ----
  const int h = wave;
  f32x4 z4 = {0.f, 0.f, 0.f, 0.f};
  bf16x8 kb[4];
#pragma unroll
  for (int nt = 0; nt < 4; ++nt) {
    int srow = nt * 16 + c16;
    kb[nt] = *(const bf16x8*)(smem + K_OFF + srow * 256 + ((h * 64 + g * 16) ^ ((srow & 7) << 4)));
  }
  f32x4 sc[4][4];
#pragma unroll
  for (int mt = 0; mt < 4; ++mt) {
    int qrow = mt * 16 + c16;
    bf16x8 qa = *(const bf16x8*)(smem + Q_OFF + qrow * 256 + ((h * 64 + g * 16) ^ ((qrow & 7) << 4)));
#pragma unroll
    for (int nt = 0; nt < 4; ++nt) sc[mt][nt] = MFMA16(qa, kb[nt], z4);
  }
  int widc[4];
#pragma unroll
  for (int nt = 0; nt < 4; ++nt) {
    int s2 = nt * 16 + c16;
    int r0 = (wh * 8 + (s2 >> 3) + ss) & 127;
    int c0 = (ww * 8 + (s2 & 7) + ss) & 127;
    widc[nt] = (r0 >> 3) * 16 + (c0 >> 3);
  }
  const float scale = 0.17677669529663687f;  // 1/sqrt(32)
#pragma unroll
  for (int mt = 0; mt < 4; ++mt) {
#pragma unroll
    for (int r = 0; r < 4; ++r) {
      const int s1 = mt * 16 + g * 4 + r;
      int r0 = (wh * 8 + (s1 >> 3) + ss) & 127;
      int c0 = (ww * 8 + (s1 & 7) + ss) & 127;
      const int w1 = (r0 >> 3) * 16 + (c0 >> 3);
      float mx = -1e30f;
#pragma unroll
      for (int nt = 0; nt < 4; ++nt) {
        int s2 = nt * 16 + c16;
        float v = sc[mt][nt][r] * scale + bias_full[h * 4096 + s1 * 64 + s2];
        if (shift && (w1 != widc[nt])) v -= 100.f;
        sc[mt][nt][r] = v;
        mx = fmaxf(mx, v);
      }
      mx = fmaxf(mx, __shfl_xor(mx, 1));
      mx = fmaxf(mx, __shfl_xor(mx, 2));
      mx = fmaxf(mx, __shfl_xor(mx, 4));
      mx = fmaxf(mx, __shfl_xor(mx, 8));
      float sum = 0.f;
#pragma unroll
      for (int nt = 0; nt < 4; ++nt) {
        float e = __expf(sc[mt][nt][r] - mx);
        sc[mt][nt][r] = e;
        sum += e;
      }
      sum += __shfl_xor(sum, 1);
      sum += __shfl_xor(sum, 2);
      sum += __shfl_xor(sum, 4);
      sum += __shfl_xor(sum, 8);
      float inv = 1.0f / sum;
#pragma unroll
      for (int nt = 0; nt < 4; ++nt) {
        int s2 = nt * 16 + c16;
        *(unsigned short*)(smem + XP_OFF + h * 8192 + s1 * 128 +
                           ((s2 * 2) ^ ((s1 & 7) << 4))) = f2bf(sc[mt][nt][r] * inv);
      }
    }
  }

  // ---- Phase D: PV (reads own P + Vt; no barrier needed) ----
  f32x4 o[4][2];
#pragma unroll
  for (int mt = 0; mt < 4; ++mt) { o[mt][0] = z4; o[mt][1] = z4; }
#pragma unroll
  for (int ks = 0; ks < 2; ++ks) {
    bf16x8 vb[2];
#pragma unroll
    for (int nt = 0; nt < 2; ++nt) {
      int n = h * 32 + nt * 16 + c16;
      vb[nt] = *(const bf16x8*)(smem + VT_OFF + n * 128 + ((ks * 64 + g * 16) ^ ((n & 7) << 4)));
    }
#pragma unroll
    for (int mt = 0; mt < 4; ++mt) {
      int s1 = mt * 16 + c16;
      bf16x8 pa = *(const bf16x8*)(smem + XP_OFF + h * 8192 + s1 * 128 +
                                   ((ks * 64 + g * 16) ^ ((s1 & 7) << 4)));
      o[mt][0] = MFMA16(pa, vb[0], o[mt][0]);
      o[mt][1] = MFMA16(pa, vb[1], o[mt][1]);
    }
  }
  __syncthreads();  // all waves done reading K/Q before attn-out overwrites K region

  // ---- Phase E: stage attn-out (bf16) into K region ----
#pragma unroll
  for (int mt = 0; mt < 4; ++mt)
#pragma unroll
    for (int nt = 0; nt < 2; ++nt)
#pragma unroll
      for (int r = 0; r < 4; ++r) {
        int row = mt * 16 + g * 4 + r;
        int col = h * 32 + nt * 16 + c16;
        *(unsigned short*)(smem + K_OFF + row * 256 + ((col * 2) ^ ((row & 7) << 4))) =
            f2bf(o[mt][nt][r]);
      }
  __syncthreads();

  // ---- Phase F: output projection -> global fp32 ----
  {
    f32x4 acc[8];
#pragma unroll
    for (int nt = 0; nt < 8; ++nt) acc[nt] = z4;
    const int arow = wave * 16 + c16;
    const int asw = (arow & 7) << 4;
#pragma unroll
    for (int kk = 0; kk < 4; ++kk) {
      bf16x8 a = *(const bf16x8*)(smem + K_OFF + arow * 256 + ((kk * 64 + g * 16) ^ asw));
#pragma unroll
      for (int nt = 0; nt < 8; ++nt) {
        bf16x8 bfr = *(const bf16x8*)(wt + 49152 + (nt * 16 + c16) * 128 + kk * 32 + g * 8);
        acc[nt] = MFMA16(a, bfr, acc[nt]);
      }
    }
#pragma unroll
    for (int nt = 0; nt < 8; ++nt) {
      int n = nt * 16 + c16;
      float bn = bo[n];
#pragma unroll
      for (int r = 0; r < 4; ++r) {
        int row = wave * 16 + g * 4 + r;
        out[(size_t)win * 8192 + (size_t)(row * 128 + n)] = acc[nt][r] + bn;
      }
    }
  }
}

extern "C" void kernel_launch(void* const* d_in, const int* in_sizes, int n_in,
                              void* d_out, int out_size, void* d_ws, size_t ws_size,
                              hipStream_t stream) {
  const float* x = (const float*)d_in[0];
  const float* wq = (const float*)d_in[1];
  const float* bq = (const float*)d_in[2];
  const float* wk = (const float*)d_in[3];
  const float* bk = (const float*)d_in[4];
  const float* wv = (const float*)d_in[5];
  const float* bv = (const float*)d_in[6];
  const float* wo = (const float*)d_in[7];
  const float* bo = (const float*)d_in[8];
  const float* bias_table = (const float*)d_in[9];
  const int* shiftp = (const int*)d_in[10];

  unsigned short* wt = (unsigned short*)d_ws;                    // 4*128*128 bf16 = 128KB
  float* bias_full = (float*)((char*)d_ws + 131072);             // 4*64*64 f32 = 64KB

  prep_kernel<<<256, 256, 0, stream>>>(wq, wk, wv, wo, bias_table, wt, bias_full);
  winattn_kernel<<<4096, 256, 0, stream>>>(x, bq, bk, bv, bo, wt, bias_full, shiftp,
                                           (float*)d_out);
}

// Round 2
// 190.896 us; speedup vs baseline: 1.5869x; 1.5869x over previous
//
#include <hip/hip_runtime.h>

// Swin shifted-window MHSA, fully fused per-window kernel, v2.
// 1 block = 1 window (S=64 tokens, C=128), 256 threads = 4 waves, wave h = head h.
// Register-resident attention: swapped Q/K projections + custom MFMA k-mapping
// make QK^T, softmax, and PV run entirely out of registers. LDS only for the
// gathered window (16KB) and the attn-out staging before the output projection.

typedef __attribute__((ext_vector_type(8))) short bf16x8;   // 8 bf16 = 4 VGPR
typedef __attribute__((ext_vector_type(4))) float f32x4;    // MFMA C/D

#define MFMA16(a, b, c) __builtin_amdgcn_mfma_f32_16x16x32_bf16((a), (b), (c), 0, 0, 0)

__device__ __forceinline__ unsigned short f2bf(float f) {
  union { float f; unsigned int u; } v; v.f = f;
  unsigned int r = v.u + 0x7fffu + ((v.u >> 16) & 1u);   // RNE
  return (unsigned short)(r >> 16);
}

__device__ __forceinline__ bf16x8 pack8(f32x4 a, f32x4 b) {
  bf16x8 r;
  r[0] = (short)f2bf(a[0]); r[1] = (short)f2bf(a[1]);
  r[2] = (short)f2bf(a[2]); r[3] = (short)f2bf(a[3]);
  r[4] = (short)f2bf(b[0]); r[5] = (short)f2bf(b[1]);
  r[6] = (short)f2bf(b[2]); r[7] = (short)f2bf(b[3]);
  return r;
}

// prep: transpose weights to bf16 Wt[n][k] (4 matrices) + expand rel-pos bias to [4][64][64] f32.
__global__ void prep_kernel(const float* __restrict__ wq, const float* __restrict__ wk,
                            const float* __restrict__ wv, const float* __restrict__ wo,
                            const float* __restrict__ bias_table,
                            unsigned short* __restrict__ wt, float* __restrict__ bias_full) {
  int tid = blockIdx.x * 256 + threadIdx.x;            // 65536 threads
  int m = tid >> 14, idx = tid & 16383;
  int n = idx >> 7, k = idx & 127;
  const float* w = (m == 0) ? wq : (m == 1) ? wk : (m == 2) ? wv : wo;
  wt[m * 16384 + n * 128 + k] = f2bf(w[k * 128 + n]);
  if (tid < 16384) {                                    // bias_full[h][s1][s2]
    int h = tid >> 12, r = tid & 4095;
    int s1 = r >> 6, s2 = r & 63;
    int rel = ((s1 >> 3) - (s2 >> 3) + 7) * 15 + ((s1 & 7) - (s2 & 7) + 7);
    bias_full[tid] = bias_table[rel * 4 + h];
  }
}

__global__ __launch_bounds__(256, 3) void winattn_kernel(
    const float* __restrict__ x,
    const float* __restrict__ bq, const float* __restrict__ bk,
    const float* __restrict__ bv, const float* __restrict__ bo,
    const unsigned short* __restrict__ wt,
    const float* __restrict__ bias_full,
    const int* __restrict__ shiftp,
    float* __restrict__ out) {
  __shared__ __align__(16) char smem[16384];   // Xw [64][128]bf16 swizzled; later attn-out
  const int tid = threadIdx.x;
  const int h = tid >> 6, lane = tid & 63;
  const int g = lane >> 4, c16 = lane & 15;
  const int win = blockIdx.x;
  const int bb = win >> 8, widx = win & 255;
  const int wh = widx >> 4, ww = widx & 15;
  const int shift = shiftp[0];
  const int ss = shift ? 4 : 0;

  // ---- Phase A: gather shifted window tokens -> Xw (bf16, swizzled) ----
#pragma unroll
  for (int it = 0; it < 4; ++it) {
    int cid = tid + it * 256;                 // 1024 chunks of 8 channels
    int s = cid >> 4, cc = (cid & 15) << 3;
    int r0 = (wh * 8 + (s >> 3) + ss) & 127;  // roll(-ss): src = pos + ss (mod 128)
    int c0 = (ww * 8 + (s & 7) + ss) & 127;
    const float* src = x + ((bb * 16384 + r0 * 128 + c0) * 128 + cc);
    float4 lo = *(const float4*)src;
    float4 hi = *(const float4*)(src + 4);
    bf16x8 v;
    v[0] = (short)f2bf(lo.x); v[1] = (short)f2bf(lo.y);
    v[2] = (short)f2bf(lo.z); v[3] = (short)f2bf(lo.w);
    v[4] = (short)f2bf(hi.x); v[5] = (short)f2bf(hi.y);
    v[6] = (short)f2bf(hi.z); v[7] = (short)f2bf(hi.w);
    *(bf16x8*)(smem + s * 256 + ((cc * 2) ^ ((s & 7) << 4))) = v;
  }
  __syncthreads();

  const f32x4 z4 = {0.f, 0.f, 0.f, 0.f};

  // ---- Phase B: fused Q^T / K^T / V projections for this head ----
  // Q^T,K^T swapped: D[ch][s1] = Wt(rows ch) x Xw^T(cols s1).  V normal: D[s2][d].
  f32x4 qacc[2][4], kacc[2][4], vacc[4][2];
#pragma unroll
  for (int i = 0; i < 4; ++i) {
    qacc[0][i] = z4; qacc[1][i] = z4;
    kacc[0][i] = z4; kacc[1][i] = z4;
    vacc[i][0] = z4; vacc[i][1] = z4;
  }
  const unsigned short* wq_ = wt + (h * 32 + c16) * 128;
  const unsigned short* wk_ = wt + 16384 + (h * 32 + c16) * 128;
  const unsigned short* wv_ = wt + 32768 + (h * 32 + c16) * 128;
#pragma unroll
  for (int kk = 0; kk < 4; ++kk) {
    const int co = kk * 32 + g * 8;
    bf16x8 xfr[4];
#pragma unroll
    for (int t = 0; t < 4; ++t) {
      int row = t * 16 + c16;
      xfr[t] = *(const bf16x8*)(smem + row * 256 + ((co * 2) ^ ((row & 7) << 4)));
    }
    bf16x8 wqf0 = *(const bf16x8*)(wq_ + co);
    bf16x8 wqf1 = *(const bf16x8*)(wq_ + 2048 + co);
    bf16x8 wkf0 = *(const bf16x8*)(wk_ + co);
    bf16x8 wkf1 = *(const bf16x8*)(wk_ + 2048 + co);
    bf16x8 wvf0 = *(const bf16x8*)(wv_ + co);
    bf16x8 wvf1 = *(const bf16x8*)(wv_ + 2048 + co);
#pragma unroll
    for (int t = 0; t < 4; ++t) {
      qacc[0][t] = MFMA16(wqf0, xfr[t], qacc[0][t]);
      qacc[1][t] = MFMA16(wqf1, xfr[t], qacc[1][t]);
      kacc[0][t] = MFMA16(wkf0, xfr[t], kacc[0][t]);
      kacc[1][t] = MFMA16(wkf1, xfr[t], kacc[1][t]);
      vacc[t][0] = MFMA16(xfr[t], wvf0, vacc[t][0]);
      vacc[t][1] = MFMA16(xfr[t], wvf1, vacc[t][1]);
    }
  }

  // bias (+ scale folded into Q) and pack to bf16 fragments with k-mapping
  // pi(g,j) = (j>>2)*16 + g*4 + (j&3)
  bf16x8 qb16[4], kb16[4], vb16[2][2];
  {
    const float scale = 0.17677669529663687f;  // 1/sqrt(32)
    f32x4 bq4[2], bk4[2];
    bq4[0] = *(const f32x4*)(bq + h * 32 + g * 4);
    bq4[1] = *(const f32x4*)(bq + h * 32 + 16 + g * 4);
    bk4[0] = *(const f32x4*)(bk + h * 32 + g * 4);
    bk4[1] = *(const f32x4*)(bk + h * 32 + 16 + g * 4);
#pragma unroll
    for (int t = 0; t < 4; ++t) {
      f32x4 q0, q1, k0, k1;
#pragma unroll
      for (int r = 0; r < 4; ++r) {
        q0[r] = (qacc[0][t][r] + bq4[0][r]) * scale;
        q1[r] = (qacc[1][t][r] + bq4[1][r]) * scale;
        k0[r] = kacc[0][t][r] + bk4[0][r];
        k1[r] = kacc[1][t][r] + bk4[1][r];
      }
      qb16[t] = pack8(q0, q1);
      kb16[t] = pack8(k0, k1);
    }
    float bv0 = bv[h * 32 + c16];
    float bv1 = bv[h * 32 + 16 + c16];
#pragma unroll
    for (int ks = 0; ks < 2; ++ks) {
      f32x4 v00, v10, v01, v11;
#pragma unroll
      for (int r = 0; r < 4; ++r) {
        v00[r] = vacc[2 * ks][0][r] + bv0;
        v10[r] = vacc[2 * ks + 1][0][r] + bv0;
        v01[r] = vacc[2 * ks][1][r] + bv1;
        v11[r] = vacc[2 * ks + 1][1][r] + bv1;
      }
      vb16[ks][0] = pack8(v00, v10);
      vb16[ks][1] = pack8(v01, v11);
    }
  }

  // ---- Phase C: QK^T entirely from registers. sc[a][b]: S^T[s2=a*16+g*4+r][s1=b*16+c16]
  f32x4 sc[4][4];
#pragma unroll
  for (int a = 0; a < 4; ++a)
#pragma unroll
    for (int b = 0; b < 4; ++b) sc[a][b] = MFMA16(kb16[a], qb16[b], z4);

  // window-id for shift mask
  int w1i[4] = {0, 0, 0, 0};
  int w2i[4][4] = {};
  if (shift) {
#pragma unroll
    for (int b = 0; b < 4; ++b) {
      int s1 = b * 16 + c16;
      int r0 = (wh * 8 + (s1 >> 3) + ss) & 127;
      int c0 = (ww * 8 + (s1 & 7) + ss) & 127;
      w1i[b] = (r0 >> 3) * 16 + (c0 >> 3);
    }
#pragma unroll
    for (int a = 0; a < 4; ++a)
#pragma unroll
      for (int r = 0; r < 4; ++r) {
        int s2 = a * 16 + g * 4 + r;
        int r0 = (wh * 8 + (s2 >> 3) + ss) & 127;
        int c0 = (ww * 8 + (s2 & 7) + ss) & 127;
        w2i[a][r] = (r0 >> 3) * 16 + (c0 >> 3);
      }
  }

  // ---- softmax over s2 (per s1 row = (b,c16)): local 16 + shfl over g ----
  bf16x8 pa[4][2];
  const float* bfh = bias_full + h * 4096 + c16 * 64 + g * 4;
#pragma unroll
  for (int b = 0; b < 4; ++b) {
    const float* bfr = bfh + b * 1024;
    f32x4 bia[4];
#pragma unroll
    for (int a = 0; a < 4; ++a) bia[a] = *(const f32x4*)(bfr + a * 16);
    float mx = -1e30f;
#pragma unroll
    for (int a = 0; a < 4; ++a)
#pragma unroll
      for (int r = 0; r < 4; ++r) {
        float v = sc[a][b][r] + bia[a][r];
        if (shift && (w1i[b] != w2i[a][r])) v -= 100.f;
        sc[a][b][r] = v;
        mx = fmaxf(mx, v);
      }
    mx = fmaxf(mx, __shfl_xor(mx, 16));
    mx = fmaxf(mx, __shfl_xor(mx, 32));
    float sum = 0.f;
#pragma unroll
    for (int a = 0; a < 4; ++a)
#pragma unroll
      for (int r = 0; r < 4; ++r) {
        float e = __expf(sc[a][b][r] - mx);
        sc[a][b][r] = e;
        sum += e;
      }
    sum += __shfl_xor(sum, 16);
    sum += __shfl_xor(sum, 32);
    float inv = 1.0f / sum;
#pragma unroll
    for (int a = 0; a < 4; ++a)
#pragma unroll
      for (int r = 0; r < 4; ++r) sc[a][b][r] *= inv;
    pa[b][0] = pack8(sc[0][b], sc[1][b]);
    pa[b][1] = pack8(sc[2][b], sc[3][b]);
  }

  // ---- Phase D: PV from registers. o[b][nt]: O[s1=b*16+g*4+r][d=h*32+nt*16+c16]
  f32x4 o[4][2];
#pragma unroll
  for (int b = 0; b < 4; ++b) { o[b][0] = z4; o[b][1] = z4; }
#pragma unroll
  for (int b = 0; b < 4; ++b)
#pragma unroll
    for (int ks = 0; ks < 2; ++ks) {
      o[b][0] = MFMA16(pa[b][ks], vb16[ks][0], o[b][0]);
      o[b][1] = MFMA16(pa[b][ks], vb16[ks][1], o[b][1]);
    }

  __syncthreads();  // all waves done with Xw reads; reuse smem for attn-out

  // ---- Phase E: stage attn-out (bf16, swizzled rows) ----
#pragma unroll
  for (int b = 0; b < 4; ++b)
#pragma unroll
    for (int nt = 0; nt < 2; ++nt)
#pragma unroll
      for (int r = 0; r < 4; ++r) {
        int row = b * 16 + g * 4 + r;
        int col = h * 32 + nt * 16 + c16;
        *(unsigned short*)(smem + row * 256 + ((col * 2) ^ ((row & 7) << 4))) =
            f2bf(o[b][nt][r]);
      }
  __syncthreads();

  // ---- Phase F: output projection -> global fp32 (wave h: rows h*16..h*16+15) ----
  {
    f32x4 acc[8];
#pragma unroll
    for (int nt = 0; nt < 8; ++nt) acc[nt] = z4;
    const int arow = h * 16 + c16;
    const int asw = (arow & 7) << 4;
#pragma unroll
    for (int kk = 0; kk < 4; ++kk) {
      const int co = kk * 32 + g * 8;
      bf16x8 a = *(const bf16x8*)(smem + arow * 256 + ((co * 2) ^ asw));
#pragma unroll
      for (int nt = 0; nt < 8; ++nt) {
        bf16x8 bfr = *(const bf16x8*)(wt + 49152 + (nt * 16 + c16) * 128 + co);
        acc[nt] = MFMA16(a, bfr, acc[nt]);
      }
    }
#pragma unroll
    for (int nt = 0; nt < 8; ++nt) {
      int n = nt * 16 + c16;
      float bn = bo[n];
#pragma unroll
      for (int r = 0; r < 4; ++r) {
        int row = h * 16 + g * 4 + r;
        out[(size_t)win * 8192 + (size_t)(row * 128 + n)] = acc[nt][r] + bn;
      }
    }
  }
}

extern "C" void kernel_launch(void* const* d_in, const int* in_sizes, int n_in,
                              void* d_out, int out_size, void* d_ws, size_t ws_size,
                              hipStream_t stream) {
  const float* x = (const float*)d_in[0];
  const float* wq = (const float*)d_in[1];
  const float* bq = (const float*)d_in[2];
  const float* wk = (const float*)d_in[3];
  const float* bk = (const float*)d_in[4];
  const float* wv = (const float*)d_in[5];
  const float* bv = (const float*)d_in[6];
  const float* wo = (const float*)d_in[7];
  const float* bo = (const float*)d_in[8];
  const float* bias_table = (const float*)d_in[9];
  const int* shiftp = (const int*)d_in[10];

  unsigned short* wt = (unsigned short*)d_ws;                    // 4*128*128 bf16 = 128KB
  float* bias_full = (float*)((char*)d_ws + 131072);             // 4*64*64 f32 = 64KB

  prep_kernel<<<256, 256, 0, stream>>>(wq, wk, wv, wo, bias_table, wt, bias_full);
  winattn_kernel<<<4096, 256, 0, stream>>>(x, bq, bk, bv, bo, wt, bias_full, shiftp,
                                           (float*)d_out);
}